// Round 2
// baseline (475.956 us; speedup 1.0000x reference)
//
#include <hip/hip_runtime.h>

#define H 64
#define NOBJ 512
#define BATCH 128

typedef __attribute__((ext_vector_type(8))) short s16x8;
typedef __attribute__((ext_vector_type(4))) float f32x4;
typedef __attribute__((ext_vector_type(4))) unsigned short u16x4;
typedef __attribute__((ext_vector_type(8))) unsigned short u16x8;

__device__ __forceinline__ unsigned short f2bf(float f) {
    unsigned int u = __float_as_uint(f);
    u += 0x7FFFu + ((u >> 16) & 1u);          // round-to-nearest-even
    return (unsigned short)(u >> 16);
}
__device__ __forceinline__ float bf2f(unsigned short h) {
    return __uint_as_float((unsigned int)h << 16);
}

#define MFMA16(a, b, c) __builtin_amdgcn_mfma_f32_16x16x32_bf16(a, b, c, 0, 0, 0)

// ---------------- Kernel 1: fused q/k/v projections -> bf16 (hi/lo split) ----
// x: [N,B,H], W: [H,H], bias: [H] -> y: [B,N,H] bf16. q,k: hi+lo pair; v: hi only.
__global__ __launch_bounds__(256) void proj_kernel(
    const float* __restrict__ q, const float* __restrict__ k, const float* __restrict__ v,
    const float* __restrict__ Wq, const float* __restrict__ bq,
    const float* __restrict__ Wk, const float* __restrict__ bk,
    const float* __restrict__ Wv, const float* __restrict__ bv,
    unsigned short* __restrict__ qh, unsigned short* __restrict__ ql,
    unsigned short* __restrict__ kh, unsigned short* __restrict__ kl,
    unsigned short* __restrict__ vb)
{
    const float* x; const float* W; const float* bias;
    unsigned short* yh; unsigned short* yl;
    if (blockIdx.y == 0)      { x = q; W = Wq; bias = bq; yh = qh; yl = ql; }
    else if (blockIdx.y == 1) { x = k; W = Wk; bias = bk; yh = kh; yl = kl; }
    else                      { x = v; W = Wv; bias = bv; yh = vb; yl = nullptr; }
    const bool split = (blockIdx.y < 2);

    const int tid  = threadIdx.x;
    const int lane = tid & 63;
    const int wid  = __builtin_amdgcn_readfirstlane(tid >> 6);

    float w[64];
    {
        const float4* Wr = (const float4*)(W + (size_t)lane * 64);
        #pragma unroll
        for (int hc = 0; hc < 16; ++hc) {
            float4 t = Wr[hc];
            w[hc * 4 + 0] = t.x; w[hc * 4 + 1] = t.y;
            w[hc * 4 + 2] = t.z; w[hc * 4 + 3] = t.w;
        }
    }
    const float bval = bias[lane];

    const int r0 = blockIdx.x * 256 + wid * 64;
    for (int r = 0; r < 64; ++r) {
        const int row = r0 + r;                             // wave-uniform
        const float* __restrict__ xr = x + (size_t)row * H; // uniform -> s_load
        float a0 = bval, a1 = 0.0f, a2 = 0.0f, a3 = 0.0f;
        #pragma unroll
        for (int h = 0; h < 64; h += 4) {
            a0 = fmaf(xr[h + 0], w[h + 0], a0);
            a1 = fmaf(xr[h + 1], w[h + 1], a1);
            a2 = fmaf(xr[h + 2], w[h + 2], a2);
            a3 = fmaf(xr[h + 3], w[h + 3], a3);
        }
        const float val = (a0 + a1) + (a2 + a3);
        const int n = row >> 7, b = row & 127;
        const size_t idx = ((size_t)b * NOBJ + n) * H + lane;
        const unsigned short hi = f2bf(val);
        yh[idx] = hi;
        if (split) yl[idx] = f2bf(val - bf2f(hi));
    }
}

// ---------------- Kernel 2: transpose vb [B][N][H] -> vt [B][H][N] (bf16) ----
__global__ __launch_bounds__(256) void vt_kernel(
    const unsigned short* __restrict__ vb, unsigned short* __restrict__ vt)
{
    __shared__ unsigned short t[128][72];   // 128 n x 64 h, stride 144B
    const int tid = threadIdx.x;
    const int b = blockIdx.y, n0 = blockIdx.x * 128;

    const int r = tid >> 3, c = tid & 7;
    #pragma unroll
    for (int p = 0; p < 4; ++p) {
        const int n = p * 32 + r;
        u16x8 d = *(const u16x8*)(vb + ((size_t)b * NOBJ + n0 + n) * H + c * 8);
        *(u16x8*)&t[n][c * 8] = d;
    }
    __syncthreads();
    const int h = tid & 63, nc = (tid >> 6) * 32;
    unsigned short* dst = vt + ((size_t)b * H + h) * NOBJ + n0 + nc;
    #pragma unroll
    for (int i = 0; i < 4; ++i) {
        u16x8 d;
        #pragma unroll
        for (int j = 0; j < 8; ++j) d[j] = t[nc + i * 8 + j][h];
        *(u16x8*)(dst + i * 8) = d;
    }
}

// ---------------- Kernel 3: MFMA attention, 8 waves / 512 threads ----------------
// grid (32, 128): x = n-tile (16 rows), y = b. Score phase: wave w owns m-range
// [64w, 64w+64). AV phase: wave w = (h-tile w&3, m-half w>>2), partials combined
// through a 4 KB LDS buffer. LDS ~37.3 KB -> 4 blocks/CU = 32 waves/CU (vs 16 before).
// VGPR must stay <= 64 for 8 waves/SIMD: e values are NOT kept in registers across
// the barrier; the A-write reconstructs e = hi+lo from the LDS strips.
__global__ __launch_bounds__(512, 8) void attn_kernel(
    const unsigned short* __restrict__ qh, const unsigned short* __restrict__ ql,
    const unsigned short* __restrict__ kh, const unsigned short* __restrict__ kl,
    const unsigned short* __restrict__ vt, const float* __restrict__ mask,
    float* __restrict__ out, float* __restrict__ Aout)
{
    __shared__ unsigned short sch[16][520];  // e hi strip, stride 260 dwords
    __shared__ unsigned short scl[16][520];  // e lo strip
    __shared__ float pbuf[16][68];           // AV partials (m-half 1), 4.25 KB
    __shared__ float rsum[8][16];
    __shared__ float inv[16];

    const int tid  = threadIdx.x;
    const int lane = tid & 63;
    const int w    = __builtin_amdgcn_readfirstlane(tid >> 6);   // 0..7
    const int l15  = lane & 15;
    const int lg   = lane >> 4;
    const int n0   = blockIdx.x * 16;
    const int b    = blockIdx.y;

    // q fragments (B-operand): col n = l15, k = h contiguous
    const size_t qoff = ((size_t)b * NOBJ + n0 + l15) * H + lg * 8;
    const s16x8 qfh0 = *(const s16x8*)(qh + qoff);
    const s16x8 qfh1 = *(const s16x8*)(qh + qoff + 32);
    const s16x8 qfl0 = *(const s16x8*)(ql + qoff);
    const s16x8 qfl1 = *(const s16x8*)(ql + qoff + 32);

    const unsigned short* khp = kh + ((size_t)b * NOBJ + w * 64 + l15) * H + lg * 8;
    const unsigned short* klp = kl + ((size_t)b * NOBJ + w * 64 + l15) * H + lg * 8;
    const float* mskp = mask + ((size_t)b * NOBJ + n0 + l15) * NOBJ + w * 64 + lg * 4;

    // prefetch all 4 mask quads (independent of MFMA chain)
    float4 msk[4];
    #pragma unroll
    for (int mt = 0; mt < 4; ++mt) msk[mt] = *(const float4*)(mskp + mt * 16);

    float rp = 0.0f;

    #pragma unroll
    for (int mt = 0; mt < 4; ++mt) {
        // k fragments (A-operand): row m = l15 within tile, k = h contiguous
        const s16x8 kf_h0 = *(const s16x8*)(khp + (mt * 16) * H);
        const s16x8 kf_h1 = *(const s16x8*)(khp + (mt * 16) * H + 32);
        const s16x8 kf_l0 = *(const s16x8*)(klp + (mt * 16) * H);
        const s16x8 kf_l1 = *(const s16x8*)(klp + (mt * 16) * H + 32);

        f32x4 acc = {0.0f, 0.0f, 0.0f, 0.0f};           // C[m][n]: col n = l15
        acc = MFMA16(kf_h0, qfh0, acc);
        acc = MFMA16(kf_h1, qfh1, acc);
        acc = MFMA16(kf_h0, qfl0, acc);
        acc = MFMA16(kf_h1, qfl1, acc);
        acc = MFMA16(kf_l0, qfh0, acc);
        acc = MFMA16(kf_l1, qfh1, acc);

        f32x4 e;
        e[0] = __expf(acc[0] * 0.125f) * msk[mt].x;
        e[1] = __expf(acc[1] * 0.125f) * msk[mt].y;
        e[2] = __expf(acc[2] * 0.125f) * msk[mt].z;
        e[3] = __expf(acc[3] * 0.125f) * msk[mt].w;
        rp += (e[0] + e[1]) + (e[2] + e[3]);            // 4 m, same n -> scalar partial

        u16x4 hv, lv;
        #pragma unroll
        for (int r = 0; r < 4; ++r) {
            const unsigned short hb = f2bf(e[r]);
            hv[r] = hb;
            lv[r] = f2bf(e[r] - bf2f(hb));
        }
        const int mo = w * 64 + mt * 16 + lg * 4;
        *(u16x4*)&sch[l15][mo] = hv;
        *(u16x4*)&scl[l15][mo] = lv;
    }

    // row sums: combine the 4 lane-groups sharing n = l15, then the 8 waves
    rp += __shfl_xor(rp, 16);
    rp += __shfl_xor(rp, 32);
    if (lane < 16) rsum[w][lane] = rp;
    __syncthreads();
    if (tid < 16) {
        const float s = ((rsum[0][tid] + rsum[1][tid]) + (rsum[2][tid] + rsum[3][tid]))
                      + ((rsum[4][tid] + rsum[5][tid]) + (rsum[6][tid] + rsum[7][tid]));
        inv[tid] = 1.0f / (s == 0.0f ? 1.0f : s);
    }
    __syncthreads();

    // A write: e = hi + lo from strips (rel err ~2^-17), x inv, float4 per lane
    {
        const float iv = inv[l15];
        float* Arow = Aout + ((size_t)b * NOBJ + n0 + l15) * NOBJ + w * 64 + lg * 4;
        #pragma unroll
        for (int mt = 0; mt < 4; ++mt) {
            const int mo = w * 64 + mt * 16 + lg * 4;
            const u16x4 hv = *(const u16x4*)&sch[l15][mo];
            const u16x4 lv = *(const u16x4*)&scl[l15][mo];
            float4 a4;
            a4.x = (bf2f(hv[0]) + bf2f(lv[0])) * iv;
            a4.y = (bf2f(hv[1]) + bf2f(lv[1])) * iv;
            a4.z = (bf2f(hv[2]) + bf2f(lv[2])) * iv;
            a4.w = (bf2f(hv[3]) + bf2f(lv[3])) * iv;
            *(float4*)(Arow + mt * 16) = a4;
        }
    }

    // AV: out[n][h] = inv[n] * sum_m e[n][m] * v[m][h]
    // wave w: h-tile = (w&3)*16, m-half = (w>>2)*256; partials combined via pbuf
    const int ht = w & 3, half = w >> 2;
    const unsigned short* vtp = vt + ((size_t)b * H + ht * 16 + l15) * NOBJ
                                   + half * 256 + lg * 8;
    f32x4 o0 = {0.0f, 0.0f, 0.0f, 0.0f}, o1 = {0.0f, 0.0f, 0.0f, 0.0f};
    #pragma unroll
    for (int ks = 0; ks < 8; ks += 2) {
        const int mk = half * 256 + ks * 32 + lg * 8;
        const s16x8 ah0 = *(const s16x8*)&sch[l15][mk];
        const s16x8 al0 = *(const s16x8*)&scl[l15][mk];
        const s16x8 vf0 = *(const s16x8*)(vtp + ks * 32);
        o0 = MFMA16(ah0, vf0, o0);
        o0 = MFMA16(al0, vf0, o0);
        const s16x8 ah1 = *(const s16x8*)&sch[l15][mk + 32];
        const s16x8 al1 = *(const s16x8*)&scl[l15][mk + 32];
        const s16x8 vf1 = *(const s16x8*)(vtp + ks * 32 + 32);
        o1 = MFMA16(ah1, vf1, o1);
        o1 = MFMA16(al1, vf1, o1);
    }

    if (half == 1) {
        #pragma unroll
        for (int r = 0; r < 4; ++r)
            pbuf[lg * 4 + r][ht * 16 + l15] = o0[r] + o1[r];
    }
    __syncthreads();
    if (half == 0) {
        #pragma unroll
        for (int r = 0; r < 4; ++r) {
            const int n = lg * 4 + r;                    // C row = n, col = h = l15
            const float val = (o0[r] + o1[r]) + pbuf[n][ht * 16 + l15];
            out[((size_t)(n0 + n) * BATCH + b) * H + ht * 16 + l15] = val * inv[n];
        }
    }
}

extern "C" void kernel_launch(void* const* d_in, const int* in_sizes, int n_in,
                              void* d_out, int out_size, void* d_ws, size_t ws_size,
                              hipStream_t stream)
{
    (void)in_sizes; (void)n_in; (void)out_size; (void)ws_size;
    const float* q    = (const float*)d_in[0];
    const float* k    = (const float*)d_in[1];
    const float* v    = (const float*)d_in[2];
    const float* mask = (const float*)d_in[3];
    const float* Wq   = (const float*)d_in[4];
    const float* bq   = (const float*)d_in[5];
    const float* Wk   = (const float*)d_in[6];
    const float* bk   = (const float*)d_in[7];
    const float* Wv   = (const float*)d_in[8];
    const float* bv   = (const float*)d_in[9];

    float* out  = (float*)d_out;                                  // [N,B,H]
    float* Aout = (float*)d_out + (size_t)NOBJ * BATCH * H;       // [B,N,N]

    // workspace: 6 bf16 arrays of B*N*H = 50.33 MB total
    const size_t S = (size_t)BATCH * NOBJ * H;
    unsigned short* qh = (unsigned short*)d_ws;
    unsigned short* ql = qh + S;
    unsigned short* kh = ql + S;
    unsigned short* kl = kh + S;
    unsigned short* vb = kl + S;
    unsigned short* vt = vb + S;

    proj_kernel<<<dim3(256, 3), 256, 0, stream>>>(q, k, v, Wq, bq, Wk, bk, Wv, bv,
                                                  qh, ql, kh, kl, vb);
    vt_kernel<<<dim3(NOBJ / 128, BATCH), 256, 0, stream>>>(vb, vt);
    attn_kernel<<<dim3(NOBJ / 16, BATCH), 512, 0, stream>>>(qh, ql, kh, kl, vt, mask, out, Aout);
}

// Round 3
// 401.493 us; speedup vs baseline: 1.1855x; 1.1855x over previous
//
#include <hip/hip_runtime.h>

#define H 64
#define NOBJ 512
#define BATCH 128

typedef __attribute__((ext_vector_type(8))) short s16x8;
typedef __attribute__((ext_vector_type(4))) float f32x4;
typedef __attribute__((ext_vector_type(4))) unsigned short u16x4;
typedef __attribute__((ext_vector_type(8))) unsigned short u16x8;

__device__ __forceinline__ unsigned short f2bf(float f) {
    unsigned int u = __float_as_uint(f);
    u += 0x7FFFu + ((u >> 16) & 1u);          // round-to-nearest-even
    return (unsigned short)(u >> 16);
}
__device__ __forceinline__ float bf2f(unsigned short h) {
    return __uint_as_float((unsigned int)h << 16);
}

#define MFMA16(a, b, c) __builtin_amdgcn_mfma_f32_16x16x32_bf16(a, b, c, 0, 0, 0)

// ---------------- Kernel 1: MFMA projections -> bf16 hi/lo, v -> vt directly ----
// grid (8, 128, 3): x = 64-n chunk, y = b, z = array {q,k,v}. block 256 = 4 waves,
// wave wt owns 16 n. 3-term split-bf16 MFMA (xh*Wh + xl*Wh + xh*Wl), fp32 acc.
// q,k: D[h][n] = W*x -> lane holds 4 consecutive h for one n -> coalesced u16x4
// hi/lo stores into [B,N,H]. v: D[n][h] = x*W -> LDS 64x64 tile -> coalesced
// vt [B,H,N] stores. Replaces the old VALU proj AND the vt transpose kernel.
__global__ __launch_bounds__(256) void proj_kernel(
    const float* __restrict__ q, const float* __restrict__ k, const float* __restrict__ v,
    const float* __restrict__ Wq, const float* __restrict__ bq,
    const float* __restrict__ Wk, const float* __restrict__ bk,
    const float* __restrict__ Wv, const float* __restrict__ bv,
    unsigned short* __restrict__ qh, unsigned short* __restrict__ ql,
    unsigned short* __restrict__ kh, unsigned short* __restrict__ kl,
    unsigned short* __restrict__ vt)
{
    __shared__ unsigned short vtile[64][72];   // [h][n], 144-B rows (16-B aligned)

    const int z = blockIdx.z;
    const float* x; const float* W; const float* bias;
    unsigned short* yh; unsigned short* yl;
    if (z == 0)      { x = q; W = Wq; bias = bq; yh = qh; yl = ql; }
    else if (z == 1) { x = k; W = Wk; bias = bk; yh = kh; yl = kl; }
    else             { x = v; W = Wv; bias = bv; yh = nullptr; yl = nullptr; }

    const int tid  = threadIdx.x;
    const int lane = tid & 63;
    const int wt   = tid >> 6;    // wave's 16-n tile
    const int l15  = lane & 15;
    const int lg   = lane >> 4;
    const int n0   = blockIdx.x * 64;
    const int b    = blockIdx.y;

    // W fragments: lane = (row ht*16+l15, k = kc*32+lg*8+j), k contiguous
    s16x8 wfh[4][2], wfl[4][2];
    #pragma unroll
    for (int ht = 0; ht < 4; ++ht) {
        #pragma unroll
        for (int kc = 0; kc < 2; ++kc) {
            const float* p = W + (ht * 16 + l15) * H + kc * 32 + lg * 8;
            float4 f0 = *(const float4*)p;
            float4 f1 = *(const float4*)(p + 4);
            float f[8] = {f0.x, f0.y, f0.z, f0.w, f1.x, f1.y, f1.z, f1.w};
            s16x8 hi8, lo8;
            #pragma unroll
            for (int j = 0; j < 8; ++j) {
                const unsigned short hb = f2bf(f[j]);
                hi8[j] = (short)hb;
                lo8[j] = (short)f2bf(f[j] - bf2f(hb));
            }
            wfh[ht][kc] = hi8; wfl[ht][kc] = lo8;
        }
    }

    // x fragments for this wave's 16 rows: n = n0+wt*16+l15, x is [N,B,H]
    const int n = n0 + wt * 16 + l15;
    const float* xr = x + ((size_t)n * BATCH + b) * H;
    s16x8 xfh[2], xfl[2];
    #pragma unroll
    for (int kc = 0; kc < 2; ++kc) {
        const float* p = xr + kc * 32 + lg * 8;
        float4 f0 = *(const float4*)p;
        float4 f1 = *(const float4*)(p + 4);
        float f[8] = {f0.x, f0.y, f0.z, f0.w, f1.x, f1.y, f1.z, f1.w};
        s16x8 hi8, lo8;
        #pragma unroll
        for (int j = 0; j < 8; ++j) {
            const unsigned short hb = f2bf(f[j]);
            hi8[j] = (short)hb;
            lo8[j] = (short)f2bf(f[j] - bf2f(hb));
        }
        xfh[kc] = hi8; xfl[kc] = lo8;
    }

    if (z < 2) {
        // D[h][n]: lane (lg,l15) holds h = ht*16+lg*4+r, n = n0+wt*16+l15
        #pragma unroll
        for (int ht = 0; ht < 4; ++ht) {
            const float4 b4 = *(const float4*)(bias + ht * 16 + lg * 4);
            f32x4 acc = {b4.x, b4.y, b4.z, b4.w};
            acc = MFMA16(wfh[ht][0], xfh[0], acc);
            acc = MFMA16(wfh[ht][1], xfh[1], acc);
            acc = MFMA16(wfh[ht][0], xfl[0], acc);
            acc = MFMA16(wfh[ht][1], xfl[1], acc);
            acc = MFMA16(wfl[ht][0], xfh[0], acc);
            acc = MFMA16(wfl[ht][1], xfh[1], acc);
            u16x4 hv, lv;
            #pragma unroll
            for (int r = 0; r < 4; ++r) {
                const unsigned short hb = f2bf(acc[r]);
                hv[r] = hb;
                lv[r] = f2bf(acc[r] - bf2f(hb));
            }
            const size_t o = ((size_t)b * NOBJ + n) * H + ht * 16 + lg * 4;
            *(u16x4*)(yh + o) = hv;
            *(u16x4*)(yl + o) = lv;
        }
    } else {
        // D[n][h]: lane holds n_local = wt*16+lg*4+r, h = ht*16+l15
        #pragma unroll
        for (int ht = 0; ht < 4; ++ht) {
            const float bs = bias[ht * 16 + l15];
            f32x4 acc = {bs, bs, bs, bs};
            acc = MFMA16(xfh[0], wfh[ht][0], acc);
            acc = MFMA16(xfh[1], wfh[ht][1], acc);
            acc = MFMA16(xfl[0], wfh[ht][0], acc);
            acc = MFMA16(xfl[1], wfh[ht][1], acc);
            acc = MFMA16(xfh[0], wfl[ht][0], acc);
            acc = MFMA16(xfh[1], wfl[ht][1], acc);
            u16x4 hv;
            #pragma unroll
            for (int r = 0; r < 4; ++r) hv[r] = f2bf(acc[r]);
            *(u16x4*)&vtile[ht * 16 + l15][wt * 16 + lg * 4] = hv;
        }
        __syncthreads();
        // coalesced vt write: thread -> (h = tid>>2, 16-short n chunk)
        const int h = tid >> 2, nc = (tid & 3) * 16;
        const u16x8 d0 = *(const u16x8*)&vtile[h][nc];
        const u16x8 d1 = *(const u16x8*)&vtile[h][nc + 8];
        unsigned short* dst = vt + ((size_t)b * H + h) * NOBJ + n0 + nc;
        *(u16x8*)dst = d0;
        *(u16x8*)(dst + 8) = d1;
    }
}

// ---------------- Kernel 2: MFMA attention (round-1 version, 160 us) ----------------
// grid (32, 128): x = n-tile (16 rows), y = b. 4 waves; wave w owns m-range 128w..128w+127
// (score phase) and h-tile 16w..16w+15 (AV phase). LDS 33.5 KB -> 4 blocks/CU.
__global__ __launch_bounds__(256, 4) void attn_kernel(
    const unsigned short* __restrict__ qh, const unsigned short* __restrict__ ql,
    const unsigned short* __restrict__ kh, const unsigned short* __restrict__ kl,
    const unsigned short* __restrict__ vt, const float* __restrict__ mask,
    float* __restrict__ out, float* __restrict__ Aout)
{
    __shared__ unsigned short sch[16][520];  // e hi strip, stride 260 dwords
    __shared__ unsigned short scl[16][520];  // e lo strip
    __shared__ float rsum[4][16];
    __shared__ float inv[16];

    const int tid  = threadIdx.x;
    const int lane = tid & 63;
    const int w    = tid >> 6;
    const int l15  = lane & 15;
    const int lg   = lane >> 4;
    const int n0   = blockIdx.x * 16;
    const int b    = blockIdx.y;

    // q fragments (B-operand): col n = l15, k = h contiguous
    const size_t qoff = ((size_t)b * NOBJ + n0 + l15) * H + lg * 8;
    const s16x8 qfh0 = *(const s16x8*)(qh + qoff);
    const s16x8 qfh1 = *(const s16x8*)(qh + qoff + 32);
    const s16x8 qfl0 = *(const s16x8*)(ql + qoff);
    const s16x8 qfl1 = *(const s16x8*)(ql + qoff + 32);

    const unsigned short* khp = kh + ((size_t)b * NOBJ + w * 128 + l15) * H + lg * 8;
    const unsigned short* klp = kl + ((size_t)b * NOBJ + w * 128 + l15) * H + lg * 8;
    const float* mskp = mask + ((size_t)b * NOBJ + n0 + l15) * NOBJ + w * 128 + lg * 4;

    f32x4 ev[8];                 // exp(score)*mask kept in regs for the fp32 A-write
    float rp = 0.0f;

    #pragma unroll
    for (int mt = 0; mt < 8; ++mt) {
        const s16x8 kf_h0 = *(const s16x8*)(khp + (mt * 16) * H);
        const s16x8 kf_h1 = *(const s16x8*)(khp + (mt * 16) * H + 32);
        const s16x8 kf_l0 = *(const s16x8*)(klp + (mt * 16) * H);
        const s16x8 kf_l1 = *(const s16x8*)(klp + (mt * 16) * H + 32);
        const float4 msk  = *(const float4*)(mskp + mt * 16);

        f32x4 acc = {0.0f, 0.0f, 0.0f, 0.0f};           // C[m][n] = sum_h k[m][h] q[n][h]
        acc = MFMA16(kf_h0, qfh0, acc);
        acc = MFMA16(kf_h1, qfh1, acc);
        acc = MFMA16(kf_h0, qfl0, acc);
        acc = MFMA16(kf_h1, qfl1, acc);
        acc = MFMA16(kf_l0, qfh0, acc);
        acc = MFMA16(kf_l1, qfh1, acc);

        f32x4 e;
        e[0] = __expf(acc[0] * 0.125f) * msk.x;
        e[1] = __expf(acc[1] * 0.125f) * msk.y;
        e[2] = __expf(acc[2] * 0.125f) * msk.z;
        e[3] = __expf(acc[3] * 0.125f) * msk.w;
        ev[mt] = e;
        rp += (e[0] + e[1]) + (e[2] + e[3]);

        u16x4 hv, lv;
        #pragma unroll
        for (int r = 0; r < 4; ++r) {
            const unsigned short hb = f2bf(e[r]);
            hv[r] = hb;
            lv[r] = f2bf(e[r] - bf2f(hb));
        }
        const int mo = w * 128 + mt * 16 + lg * 4;
        *(u16x4*)&sch[l15][mo] = hv;
        *(u16x4*)&scl[l15][mo] = lv;
    }

    rp += __shfl_xor(rp, 16);
    rp += __shfl_xor(rp, 32);
    if (lane < 16) rsum[w][lane] = rp;
    __syncthreads();
    if (tid < 16) {
        const float s = (rsum[0][tid] + rsum[1][tid]) + (rsum[2][tid] + rsum[3][tid]);
        inv[tid] = 1.0f / (s == 0.0f ? 1.0f : s);
    }
    __syncthreads();

    // A write: fp32 from registers, float4 per lane
    {
        const float iv = inv[l15];
        float* Arow = Aout + ((size_t)b * NOBJ + n0 + l15) * NOBJ + w * 128 + lg * 4;
        #pragma unroll
        for (int mt = 0; mt < 8; ++mt) {
            float4 a4;
            a4.x = ev[mt][0] * iv; a4.y = ev[mt][1] * iv;
            a4.z = ev[mt][2] * iv; a4.w = ev[mt][3] * iv;
            *(float4*)(Arow + mt * 16) = a4;
        }
    }

    // AV: out[n][h] = inv[n] * sum_m e[n][m] * v[m][h]
    const unsigned short* vtp = vt + ((size_t)b * H + w * 16 + l15) * NOBJ + lg * 8;
    f32x4 o0 = {0.0f, 0.0f, 0.0f, 0.0f}, o1 = {0.0f, 0.0f, 0.0f, 0.0f};
    #pragma unroll
    for (int ks = 0; ks < 16; ks += 2) {
        const int mk = ks * 32 + lg * 8;
        const s16x8 ah0 = *(const s16x8*)&sch[l15][mk];
        const s16x8 al0 = *(const s16x8*)&scl[l15][mk];
        const s16x8 vf0 = *(const s16x8*)(vtp + ks * 32);
        o0 = MFMA16(ah0, vf0, o0);
        o0 = MFMA16(al0, vf0, o0);
        const s16x8 ah1 = *(const s16x8*)&sch[l15][mk + 32];
        const s16x8 al1 = *(const s16x8*)&scl[l15][mk + 32];
        const s16x8 vf1 = *(const s16x8*)(vtp + ks * 32 + 32);
        o1 = MFMA16(ah1, vf1, o1);
        o1 = MFMA16(al1, vf1, o1);
    }

    #pragma unroll
    for (int r = 0; r < 4; ++r) {
        const int nn = lg * 4 + r;                       // C row = n, col = h = l15
        out[((size_t)(n0 + nn) * BATCH + b) * H + w * 16 + l15] = (o0[r] + o1[r]) * inv[nn];
    }
}

extern "C" void kernel_launch(void* const* d_in, const int* in_sizes, int n_in,
                              void* d_out, int out_size, void* d_ws, size_t ws_size,
                              hipStream_t stream)
{
    (void)in_sizes; (void)n_in; (void)out_size; (void)ws_size;
    const float* q    = (const float*)d_in[0];
    const float* k    = (const float*)d_in[1];
    const float* v    = (const float*)d_in[2];
    const float* mask = (const float*)d_in[3];
    const float* Wq   = (const float*)d_in[4];
    const float* bq   = (const float*)d_in[5];
    const float* Wk   = (const float*)d_in[6];
    const float* bk   = (const float*)d_in[7];
    const float* Wv   = (const float*)d_in[8];
    const float* bv   = (const float*)d_in[9];

    float* out  = (float*)d_out;                                  // [N,B,H]
    float* Aout = (float*)d_out + (size_t)NOBJ * BATCH * H;       // [B,N,N]

    // workspace: 5 bf16 arrays of B*N*H = 42 MB total
    const size_t S = (size_t)BATCH * NOBJ * H;
    unsigned short* qh = (unsigned short*)d_ws;
    unsigned short* ql = qh + S;
    unsigned short* kh = ql + S;
    unsigned short* kl = kh + S;
    unsigned short* vt = kl + S;

    proj_kernel<<<dim3(NOBJ / 64, BATCH, 3), 256, 0, stream>>>(
        q, k, v, Wq, bq, Wk, bk, Wv, bv, qh, ql, kh, kl, vt);
    attn_kernel<<<dim3(NOBJ / 16, BATCH), 256, 0, stream>>>(
        qh, ql, kh, kl, vt, mask, out, Aout);
}

// Round 4
// 398.104 us; speedup vs baseline: 1.1956x; 1.0085x over previous
//
#include <hip/hip_runtime.h>

#define H 64
#define NOBJ 512
#define BATCH 128

typedef __attribute__((ext_vector_type(8))) short s16x8;
typedef __attribute__((ext_vector_type(4))) float f32x4;
typedef __attribute__((ext_vector_type(4))) unsigned short u16x4;
typedef __attribute__((ext_vector_type(8))) unsigned short u16x8;

__device__ __forceinline__ unsigned short f2bf(float f) {
    unsigned int u = __float_as_uint(f);
    u += 0x7FFFu + ((u >> 16) & 1u);          // round-to-nearest-even
    return (unsigned short)(u >> 16);
}
__device__ __forceinline__ float bf2f(unsigned short h) {
    return __uint_as_float((unsigned int)h << 16);
}

#define MFMA16(a, b, c) __builtin_amdgcn_mfma_f32_16x16x32_bf16(a, b, c, 0, 0, 0)

// ---------------- Kernel 0: pack mask {0.0,1.0} -> bitmask ----------------
// 134 MB fp32 -> 4.2 MB bits; pure streaming. block 256 handles 1024 floats.
__global__ __launch_bounds__(256) void mask_pack_kernel(
    const float* __restrict__ mask, unsigned int* __restrict__ bits)
{
    __shared__ unsigned char nib[256];
    const int tid = threadIdx.x;
    const size_t base = (size_t)blockIdx.x * 1024;
    const float4 f = *(const float4*)(mask + base + (size_t)tid * 4);
    nib[tid] = (unsigned char)((unsigned)(f.x != 0.0f)
             | ((unsigned)(f.y != 0.0f) << 1)
             | ((unsigned)(f.z != 0.0f) << 2)
             | ((unsigned)(f.w != 0.0f) << 3));
    __syncthreads();
    if (tid < 32) {
        unsigned int wv = 0;
        #pragma unroll
        for (int i = 0; i < 8; ++i)
            wv |= (unsigned int)nib[tid * 8 + i] << (4 * i);
        bits[base / 32 + tid] = wv;
    }
}

// ---------------- Kernel 1: MFMA projections -> bf16 hi/lo, v -> vt directly ----
// grid (8, 128, 3): x = 64-n chunk, y = b, z = array {q,k,v}. block 256 = 4 waves.
// q,k: D[h][n] = W*x -> coalesced u16x4 hi/lo stores into [B,N,H].
// v: D[n][h] = x*W -> LDS tile -> coalesced vt [B,H,N] stores.
__global__ __launch_bounds__(256) void proj_kernel(
    const float* __restrict__ q, const float* __restrict__ k, const float* __restrict__ v,
    const float* __restrict__ Wq, const float* __restrict__ bq,
    const float* __restrict__ Wk, const float* __restrict__ bk,
    const float* __restrict__ Wv, const float* __restrict__ bv,
    unsigned short* __restrict__ qh, unsigned short* __restrict__ ql,
    unsigned short* __restrict__ kh, unsigned short* __restrict__ kl,
    unsigned short* __restrict__ vt)
{
    __shared__ unsigned short vtile[64][72];   // [h][n], 144-B rows

    const int z = blockIdx.z;
    const float* x; const float* W; const float* bias;
    unsigned short* yh; unsigned short* yl;
    if (z == 0)      { x = q; W = Wq; bias = bq; yh = qh; yl = ql; }
    else if (z == 1) { x = k; W = Wk; bias = bk; yh = kh; yl = kl; }
    else             { x = v; W = Wv; bias = bv; yh = nullptr; yl = nullptr; }

    const int tid  = threadIdx.x;
    const int lane = tid & 63;
    const int wt   = tid >> 6;
    const int l15  = lane & 15;
    const int lg   = lane >> 4;
    const int n0   = blockIdx.x * 64;
    const int b    = blockIdx.y;

    // W fragments: lane = (row ht*16+l15, k = kc*32+lg*8+j), k contiguous
    s16x8 wfh[4][2], wfl[4][2];
    #pragma unroll
    for (int ht = 0; ht < 4; ++ht) {
        #pragma unroll
        for (int kc = 0; kc < 2; ++kc) {
            const float* p = W + (ht * 16 + l15) * H + kc * 32 + lg * 8;
            float4 f0 = *(const float4*)p;
            float4 f1 = *(const float4*)(p + 4);
            float f[8] = {f0.x, f0.y, f0.z, f0.w, f1.x, f1.y, f1.z, f1.w};
            s16x8 hi8, lo8;
            #pragma unroll
            for (int j = 0; j < 8; ++j) {
                const unsigned short hb = f2bf(f[j]);
                hi8[j] = (short)hb;
                lo8[j] = (short)f2bf(f[j] - bf2f(hb));
            }
            wfh[ht][kc] = hi8; wfl[ht][kc] = lo8;
        }
    }

    // x fragments: n = n0+wt*16+l15, x is [N,B,H]
    const int n = n0 + wt * 16 + l15;
    const float* xr = x + ((size_t)n * BATCH + b) * H;
    s16x8 xfh[2], xfl[2];
    #pragma unroll
    for (int kc = 0; kc < 2; ++kc) {
        const float* p = xr + kc * 32 + lg * 8;
        float4 f0 = *(const float4*)p;
        float4 f1 = *(const float4*)(p + 4);
        float f[8] = {f0.x, f0.y, f0.z, f0.w, f1.x, f1.y, f1.z, f1.w};
        s16x8 hi8, lo8;
        #pragma unroll
        for (int j = 0; j < 8; ++j) {
            const unsigned short hb = f2bf(f[j]);
            hi8[j] = (short)hb;
            lo8[j] = (short)f2bf(f[j] - bf2f(hb));
        }
        xfh[kc] = hi8; xfl[kc] = lo8;
    }

    if (z < 2) {
        #pragma unroll
        for (int ht = 0; ht < 4; ++ht) {
            const float4 b4 = *(const float4*)(bias + ht * 16 + lg * 4);
            f32x4 acc = {b4.x, b4.y, b4.z, b4.w};
            acc = MFMA16(wfh[ht][0], xfh[0], acc);
            acc = MFMA16(wfh[ht][1], xfh[1], acc);
            acc = MFMA16(wfh[ht][0], xfl[0], acc);
            acc = MFMA16(wfh[ht][1], xfl[1], acc);
            acc = MFMA16(wfl[ht][0], xfh[0], acc);
            acc = MFMA16(wfl[ht][1], xfh[1], acc);
            u16x4 hv, lv;
            #pragma unroll
            for (int r = 0; r < 4; ++r) {
                const unsigned short hb = f2bf(acc[r]);
                hv[r] = hb;
                lv[r] = f2bf(acc[r] - bf2f(hb));
            }
            const size_t o = ((size_t)b * NOBJ + n) * H + ht * 16 + lg * 4;
            *(u16x4*)(yh + o) = hv;
            *(u16x4*)(yl + o) = lv;
        }
    } else {
        #pragma unroll
        for (int ht = 0; ht < 4; ++ht) {
            const float bs = bias[ht * 16 + l15];
            f32x4 acc = {bs, bs, bs, bs};
            acc = MFMA16(xfh[0], wfh[ht][0], acc);
            acc = MFMA16(xfh[1], wfh[ht][1], acc);
            acc = MFMA16(xfl[0], wfh[ht][0], acc);
            acc = MFMA16(xfl[1], wfh[ht][1], acc);
            acc = MFMA16(xfh[0], wfl[ht][0], acc);
            acc = MFMA16(xfh[1], wfl[ht][1], acc);
            u16x4 hv;
            #pragma unroll
            for (int r = 0; r < 4; ++r) hv[r] = f2bf(acc[r]);
            *(u16x4*)&vtile[ht * 16 + l15][wt * 16 + lg * 4] = hv;
        }
        __syncthreads();
        const int h = tid >> 2, nc = (tid & 3) * 16;
        const u16x8 d0 = *(const u16x8*)&vtile[h][nc];
        const u16x8 d1 = *(const u16x8*)&vtile[h][nc + 8];
        unsigned short* dst = vt + ((size_t)b * H + h) * NOBJ + n0 + nc;
        *(u16x8*)dst = d0;
        *(u16x8*)(dst + 8) = d1;
    }
}

// ---------------- Kernel 2: MFMA attention, bitmask + 2-deep k pipeline ----
// grid (32, 128): x = n-tile (16 rows), y = b. 4 waves; wave w owns m-range
// 128w..128w+127 (score) and h-tile 16w..16w+15 (AV). LDS 33.5 KB -> 4 blocks/CU;
// launch_bounds(256,4) -> VGPR cap 128 (free at this LDS occupancy).
__global__ __launch_bounds__(256, 4) void attn_kernel(
    const unsigned short* __restrict__ qh, const unsigned short* __restrict__ ql,
    const unsigned short* __restrict__ kh, const unsigned short* __restrict__ kl,
    const unsigned short* __restrict__ vt, const unsigned int* __restrict__ bits,
    float* __restrict__ out, float* __restrict__ Aout)
{
    __shared__ unsigned short sch[16][520];  // e hi strip, stride 260 dwords
    __shared__ unsigned short scl[16][520];  // e lo strip
    __shared__ float rsum[4][16];
    __shared__ float inv[16];

    const int tid  = threadIdx.x;
    const int lane = tid & 63;
    const int w    = tid >> 6;
    const int l15  = lane & 15;
    const int lg   = lane >> 4;
    const int n0   = blockIdx.x * 16;
    const int b    = blockIdx.y;

    // q fragments (B-operand): col n = l15, k = h contiguous
    const size_t qoff = ((size_t)b * NOBJ + n0 + l15) * H + lg * 8;
    const s16x8 qfh0 = *(const s16x8*)(qh + qoff);
    const s16x8 qfh1 = *(const s16x8*)(qh + qoff + 32);
    const s16x8 qfl0 = *(const s16x8*)(ql + qoff);
    const s16x8 qfl1 = *(const s16x8*)(ql + qoff + 32);

    const unsigned short* khp = kh + ((size_t)b * NOBJ + w * 128 + l15) * H + lg * 8;
    const unsigned short* klp = kl + ((size_t)b * NOBJ + w * 128 + l15) * H + lg * 8;

    // one uint4 = this row's mask bits for cols [w*128, w*128+128)
    const uint4 mw = *(const uint4*)(bits + ((size_t)b * NOBJ + n0 + l15) * (NOBJ / 32) + w * 4);
    const unsigned mwa[4] = {mw.x, mw.y, mw.z, mw.w};

    f32x4 ev[8];                 // exp(score)*mask kept in regs for the fp32 A-write
    float rp = 0.0f;

    // 2-deep software pipeline on k fragments
    s16x8 ka[2][4];
    ka[0][0] = *(const s16x8*)(khp);
    ka[0][1] = *(const s16x8*)(khp + 32);
    ka[0][2] = *(const s16x8*)(klp);
    ka[0][3] = *(const s16x8*)(klp + 32);

    #pragma unroll
    for (int mt = 0; mt < 8; ++mt) {
        const int cur = mt & 1, nxt = cur ^ 1;
        if (mt < 7) {
            const int o = (mt + 1) * 16 * H;
            ka[nxt][0] = *(const s16x8*)(khp + o);
            ka[nxt][1] = *(const s16x8*)(khp + o + 32);
            ka[nxt][2] = *(const s16x8*)(klp + o);
            ka[nxt][3] = *(const s16x8*)(klp + o + 32);
        }

        f32x4 acc = {0.0f, 0.0f, 0.0f, 0.0f};           // C[m][n] = sum_h k[m][h] q[n][h]
        acc = MFMA16(ka[cur][0], qfh0, acc);
        acc = MFMA16(ka[cur][1], qfh1, acc);
        acc = MFMA16(ka[cur][0], qfl0, acc);
        acc = MFMA16(ka[cur][1], qfl1, acc);
        acc = MFMA16(ka[cur][2], qfh0, acc);
        acc = MFMA16(ka[cur][3], qfh1, acc);

        // mask bits for this mt: word mt>>1, bits (mt&1)*16 + lg*4 + r
        const unsigned wsel = mwa[mt >> 1] >> (((mt & 1) << 4) + (lg << 2));
        f32x4 e;
        #pragma unroll
        for (int r = 0; r < 4; ++r) {
            const float ex = __expf(acc[r] * 0.125f);
            e[r] = ((wsel >> r) & 1u) ? ex : 0.0f;
        }
        ev[mt] = e;
        rp += (e[0] + e[1]) + (e[2] + e[3]);

        u16x4 hv, lv;
        #pragma unroll
        for (int r = 0; r < 4; ++r) {
            const unsigned short hb = f2bf(e[r]);
            hv[r] = hb;
            lv[r] = f2bf(e[r] - bf2f(hb));
        }
        const int mo = w * 128 + mt * 16 + lg * 4;
        *(u16x4*)&sch[l15][mo] = hv;
        *(u16x4*)&scl[l15][mo] = lv;
    }

    rp += __shfl_xor(rp, 16);
    rp += __shfl_xor(rp, 32);
    if (lane < 16) rsum[w][lane] = rp;
    __syncthreads();
    if (tid < 16) {
        const float s = (rsum[0][tid] + rsum[1][tid]) + (rsum[2][tid] + rsum[3][tid]);
        inv[tid] = 1.0f / (s == 0.0f ? 1.0f : s);
    }
    __syncthreads();

    // A write: fp32 from registers, float4 per lane
    {
        const float iv = inv[l15];
        float* Arow = Aout + ((size_t)b * NOBJ + n0 + l15) * NOBJ + w * 128 + lg * 4;
        #pragma unroll
        for (int mt = 0; mt < 8; ++mt) {
            float4 a4;
            a4.x = ev[mt][0] * iv; a4.y = ev[mt][1] * iv;
            a4.z = ev[mt][2] * iv; a4.w = ev[mt][3] * iv;
            *(float4*)(Arow + mt * 16) = a4;
        }
    }

    // AV: out[n][h] = inv[n] * sum_m e[n][m] * v[m][h]
    const unsigned short* vtp = vt + ((size_t)b * H + w * 16 + l15) * NOBJ + lg * 8;
    f32x4 o0 = {0.0f, 0.0f, 0.0f, 0.0f}, o1 = {0.0f, 0.0f, 0.0f, 0.0f};
    #pragma unroll
    for (int ks = 0; ks < 16; ks += 2) {
        const int mk = ks * 32 + lg * 8;
        const s16x8 ah0 = *(const s16x8*)&sch[l15][mk];
        const s16x8 al0 = *(const s16x8*)&scl[l15][mk];
        const s16x8 vf0 = *(const s16x8*)(vtp + ks * 32);
        o0 = MFMA16(ah0, vf0, o0);
        o0 = MFMA16(al0, vf0, o0);
        const s16x8 ah1 = *(const s16x8*)&sch[l15][mk + 32];
        const s16x8 al1 = *(const s16x8*)&scl[l15][mk + 32];
        const s16x8 vf1 = *(const s16x8*)(vtp + ks * 32 + 32);
        o1 = MFMA16(ah1, vf1, o1);
        o1 = MFMA16(al1, vf1, o1);
    }

    #pragma unroll
    for (int r = 0; r < 4; ++r) {
        const int nn = lg * 4 + r;                       // C row = n, col = h = l15
        out[((size_t)(n0 + nn) * BATCH + b) * H + w * 16 + l15] = (o0[r] + o1[r]) * inv[nn];
    }
}

extern "C" void kernel_launch(void* const* d_in, const int* in_sizes, int n_in,
                              void* d_out, int out_size, void* d_ws, size_t ws_size,
                              hipStream_t stream)
{
    (void)in_sizes; (void)n_in; (void)out_size; (void)ws_size;
    const float* q    = (const float*)d_in[0];
    const float* k    = (const float*)d_in[1];
    const float* v    = (const float*)d_in[2];
    const float* mask = (const float*)d_in[3];
    const float* Wq   = (const float*)d_in[4];
    const float* bq   = (const float*)d_in[5];
    const float* Wk   = (const float*)d_in[6];
    const float* bk   = (const float*)d_in[7];
    const float* Wv   = (const float*)d_in[8];
    const float* bv   = (const float*)d_in[9];

    float* out  = (float*)d_out;                                  // [N,B,H]
    float* Aout = (float*)d_out + (size_t)NOBJ * BATCH * H;       // [B,N,N]

    // workspace: 5 bf16 arrays (42 MB) + bitmask (4.2 MB)
    const size_t S = (size_t)BATCH * NOBJ * H;
    unsigned short* qh = (unsigned short*)d_ws;
    unsigned short* ql = qh + S;
    unsigned short* kh = ql + S;
    unsigned short* kl = kh + S;
    unsigned short* vt = kl + S;
    unsigned int* bits = (unsigned int*)(vt + S);

    mask_pack_kernel<<<dim3((BATCH * NOBJ * NOBJ) / 1024), 256, 0, stream>>>(mask, bits);
    proj_kernel<<<dim3(NOBJ / 64, BATCH, 3), 256, 0, stream>>>(
        q, k, v, Wq, bq, Wk, bk, Wv, bv, qh, ql, kh, kl, vt);
    attn_kernel<<<dim3(NOBJ / 16, BATCH), 256, 0, stream>>>(
        qh, ql, kh, kl, vt, bits, out, Aout);
}